// Round 13
// baseline (279.834 us; speedup 1.0000x reference)
//
#include <hip/hip_runtime.h>

#define N_NODES 50000
#define N_EDGES 800000
#define NHALFN 25000          // src-half split point
#define NBUCKET 196           // ceil(N_NODES / 256); bucket b = dst in [b*256,(b+1)*256)
#define EPB 4096              // edges per block in bucket_count / partition (16/thread)
#define EDGE_BLKS ((N_EDGES + EPB - 1) / EPB)  // 196

__device__ __forceinline__ int wave_incl_scan(int v, int lane) {
#pragma unroll
    for (int off = 1; off < 64; off <<= 1) {
        int t = __shfl_up(v, off, 64);
        if (lane >= off) v += t;
    }
    return v;
}

// ---------- CSR build via bucket counting sort ----------

__global__ __launch_bounds__(256) void bucket_count(const int* __restrict__ dst,
                                                    int* __restrict__ bcnt, int nedges) {
    __shared__ int h[NBUCKET];
    for (int i = threadIdx.x; i < NBUCKET; i += 256) h[i] = 0;
    __syncthreads();
    const int eb = blockIdx.x * EPB;
#pragma unroll
    for (int i = 0; i < 16; ++i) {
        int e = eb + i * 256 + threadIdx.x;
        if (e < nedges) atomicAdd(&h[dst[e] >> 8], 1);
    }
    __syncthreads();
    for (int i = threadIdx.x; i < NBUCKET; i += 256)
        if (h[i]) atomicAdd(&bcnt[i], h[i]);
}

__global__ __launch_bounds__(256) void bucket_scan(const int* __restrict__ bcnt,
                                                   int* __restrict__ bbase,
                                                   int* __restrict__ bcursor, int nb) {
    const int i = threadIdx.x;
    const int lane = i & 63;
    const int w = i >> 6;
    int v = (i < nb) ? bcnt[i] : 0;
    int s = wave_incl_scan(v, lane);
    __shared__ int ws[4];
    if (lane == 63) ws[w] = s;
    __syncthreads();
    int add = 0;
#pragma unroll
    for (int k = 0; k < 4; ++k)
        if (k < w) add += ws[k];
    if (i < nb) {
        int excl = s + add - v;
        bbase[i] = excl;
        bcursor[i] = excl;
    }
}

__global__ __launch_bounds__(256) void partition_kernel(const int* __restrict__ src,
                                                        const int* __restrict__ dst,
                                                        int* __restrict__ bcursor,
                                                        int* __restrict__ etmp, int nedges) {
    __shared__ int h[NBUCKET];
    __shared__ int rbase[NBUCKET];
    for (int i = threadIdx.x; i < NBUCKET; i += 256) h[i] = 0;
    __syncthreads();

    const int eb = blockIdx.x * EPB;
    int d[16], s[16];
    bool ok[16];
#pragma unroll
    for (int i = 0; i < 16; ++i) {
        int e = eb + i * 256 + threadIdx.x;
        ok[i] = e < nedges;
        d[i] = ok[i] ? dst[e] : 0;
        s[i] = ok[i] ? src[e] : 0;
        if (ok[i]) atomicAdd(&h[d[i] >> 8], 1);
    }
    __syncthreads();
    for (int i = threadIdx.x; i < NBUCKET; i += 256) {
        rbase[i] = h[i] ? atomicAdd(&bcursor[i], h[i]) : 0;
        h[i] = 0;  // reuse as local cursor
    }
    __syncthreads();
#pragma unroll
    for (int i = 0; i < 16; ++i) {
        if (ok[i]) {
            int b = d[i] >> 8;
            int pos = rbase[b] + atomicAdd(&h[b], 1);
            etmp[pos] = ((d[i] & 255) << 16) | s[i];
        }
    }
}

// One block per bucket: per-node histogram (total + low-src) + scan ->
// rowptr, rowmid (low|high split point), norm, and esrc ordered
// [low-src edges | high-src edges] within each node's run.
__global__ __launch_bounds__(256) void bucket_build(const int* __restrict__ etmp,
                                                    const int* __restrict__ bbase,
                                                    int* __restrict__ rowptr,
                                                    int* __restrict__ rowmid,
                                                    int* __restrict__ esrc,
                                                    float* __restrict__ norm,
                                                    int nnodes, int nbuckets, int nedges) {
    const int b = blockIdx.x;
    const int nodebase = b * 256;
    const int nloc = min(256, nnodes - nodebase);
    const int ebeg = bbase[b];
    const int eend = (b + 1 < nbuckets) ? bbase[b + 1] : nedges;

    __shared__ int h[256];
    __shared__ int hl[256];
    __shared__ int cl[256];
    __shared__ int ch[256];
    h[threadIdx.x] = 0;
    hl[threadIdx.x] = 0;
    __syncthreads();

    for (int e = ebeg + threadIdx.x; e < eend; e += 256) {
        int rec = etmp[e];
        atomicAdd(&h[rec >> 16], 1);
        if ((rec & 0xFFFF) < NHALFN) atomicAdd(&hl[rec >> 16], 1);
    }
    __syncthreads();

    const int lane = threadIdx.x & 63;
    const int w = threadIdx.x >> 6;
    int v = h[threadIdx.x];
    int sc = wave_incl_scan(v, lane);
    __shared__ int ws[4];
    if (lane == 63) ws[w] = sc;
    __syncthreads();
    int add = 0;
#pragma unroll
    for (int k = 0; k < 4; ++k)
        if (k < w) add += ws[k];
    const int excl = sc + add - v;

    if (threadIdx.x < nloc) {
        rowptr[nodebase + threadIdx.x] = ebeg + excl;
        rowmid[nodebase + threadIdx.x] = ebeg + excl + hl[threadIdx.x];
        norm[nodebase + threadIdx.x] = v > 0 ? rsqrtf((float)v) : 0.0f;
        if (nodebase + threadIdx.x == nnodes - 1) rowptr[nnodes] = ebeg + excl + v;
    }
    cl[threadIdx.x] = excl;
    ch[threadIdx.x] = excl + hl[threadIdx.x];
    __syncthreads();

    for (int e = ebeg + threadIdx.x; e < eend; e += 256) {
        int rec = etmp[e];
        int n = rec >> 16;
        int s = rec & 0xFFFF;
        int pos = ebeg + ((s < NHALFN) ? atomicAdd(&cl[n], 1) : atomicAdd(&ch[n], 1));
        esrc[pos] = s;
    }
}

// ---------- GEMM with output row-scale, W staged in LDS ----------
// Block = 64 rows x 64 cols (OUT=128 split into 2 col-halves).
// Output: OUT/32 slabs of [nrows x 32] floats (slice-major, 128 B rows).
template <int OUT>
__global__ __launch_bounds__(256) void gemm_rownorm(const float* __restrict__ X,
                                                    const float* __restrict__ W,
                                                    const float* __restrict__ norm,
                                                    float* __restrict__ C, int nrows) {
    constexpr int NHALF = OUT / 64;          // 2 for OUT=128, 1 for OUT=64
    const int half = (NHALF > 1) ? (blockIdx.x % NHALF) : 0;
    const int rowblk = blockIdx.x / NHALF;

    __shared__ float Wlds[128 * 64];  // 32 KB

    const int t = threadIdx.x;

    {
        const float4* __restrict__ Wg = reinterpret_cast<const float4*>(W);
        float4* Wl = reinterpret_cast<float4*>(Wlds);
#pragma unroll
        for (int s = 0; s < 8; ++s) {
            int idx = s * 256 + t;          // 0..2047
            int k  = idx >> 4;              // W row
            int cg = idx & 15;              // float4 within 64 cols
            Wl[idx] = Wg[k * (OUT / 4) + half * 16 + cg];
        }
    }
    __syncthreads();

    const int tc = t & 15;
    const int tr = t >> 4;
    const int rowbase = rowblk * 64 + tr * 4;
    const int lastrow = nrows - 1;

    float4 acc[4];
#pragma unroll
    for (int i = 0; i < 4; ++i) acc[i] = make_float4(0.f, 0.f, 0.f, 0.f);

    const float4* __restrict__ X4 = reinterpret_cast<const float4*>(X);
    const float4* __restrict__ Wl4 = reinterpret_cast<const float4*>(Wlds);
    int rIdx[4];
#pragma unroll
    for (int i = 0; i < 4; ++i) {
        int r = rowbase + i;
        rIdx[i] = r < lastrow ? r : lastrow;
    }

    for (int kk = 0; kk < 32; ++kk) {
        float4 x[4];
#pragma unroll
        for (int i = 0; i < 4; ++i) x[i] = X4[(size_t)rIdx[i] * 32 + kk];
#pragma unroll
        for (int j = 0; j < 4; ++j) {
            const int k = kk * 4 + j;
            const float4 w0 = Wl4[k * 16 + tc];
#pragma unroll
            for (int i = 0; i < 4; ++i) {
                const float* xp = reinterpret_cast<const float*>(&x[i]);
                const float xs = xp[j];
                acc[i].x += xs * w0.x;
                acc[i].y += xs * w0.y;
                acc[i].z += xs * w0.z;
                acc[i].w += xs * w0.w;
            }
        }
    }

    float4* __restrict__ C4 = reinterpret_cast<float4*>(C);
    const size_t slab = (size_t)nrows * 8;
    const int s0  = half * 2 + (tc >> 3);
    const int w0i = tc & 7;
#pragma unroll
    for (int i = 0; i < 4; ++i) {
        int r = rowbase + i;
        if (r < nrows) {
            const float nm = norm[r];
            float4 o = acc[i];
            o.x *= nm; o.y *= nm; o.z *= nm; o.w *= nm;
            C4[(size_t)s0 * slab + (size_t)r * 8 + w0i] = o;
        }
    }
}

// ---------- Two-pass column-sliced gather-aggregate (L2-fit halves) ----------
// PASS 0: gather low-src edges (slab rows < 25000 -> 3.2 MB, fits one XCD L2),
//         write raw partial sums to out.
// PASS 1: gather high-src edges (slab rows >= 25000), add partial, apply
//         norm*agg + b (+ReLU), write final.
template <int F, bool RELU, int PASS>
__global__ __launch_bounds__(256) void aggregate_pass(const float* __restrict__ feat,
                                                      const int* __restrict__ rowptr,
                                                      const int* __restrict__ rowmid,
                                                      const int* __restrict__ esrc,
                                                      const float* __restrict__ norm,
                                                      const float* __restrict__ b,
                                                      float* __restrict__ out,
                                                      int nnodes, int nchunks) {
    constexpr int NSLICE = F / 32;
    const int slice = blockIdx.x % NSLICE;
    const int chunk = blockIdx.x / NSLICE;
    const int span  = (nnodes + nchunks - 1) / nchunks;
    const int nbeg  = chunk * span;
    const int nend  = min(nnodes, nbeg + span);

    const int grp = threadIdx.x >> 3;
    const int l8  = threadIdx.x & 7;

    const float4* __restrict__ slab4 =
        reinterpret_cast<const float4*>(feat) + (size_t)slice * nnodes * 8;
    const float4 bb = reinterpret_cast<const float4*>(b)[slice * 8 + l8];

    for (int node = nbeg + grp; node < nend; node += 32) {
        const int beg = (PASS == 0) ? rowptr[node] : rowmid[node];
        const int end = (PASS == 0) ? rowmid[node] : rowptr[node + 1];

        float4 acc[8];
#pragma unroll
        for (int i = 0; i < 8; ++i) acc[i] = make_float4(0.f, 0.f, 0.f, 0.f);

        for (int e = beg; e < end; e += 8) {
            int idx[8];
#pragma unroll
            for (int i = 0; i < 8; ++i) {
                int ee = e + i;
                idx[i] = esrc[ee < end ? ee : end - 1];
            }
            float4 v[8];
#pragma unroll
            for (int i = 0; i < 8; ++i) v[i] = slab4[(size_t)idx[i] * 8 + l8];
#pragma unroll
            for (int i = 0; i < 8; ++i) {
                if (e + i < end) {
                    acc[i].x += v[i].x; acc[i].y += v[i].y;
                    acc[i].z += v[i].z; acc[i].w += v[i].w;
                }
            }
        }

        float4 a;
        a.x = ((acc[0].x + acc[1].x) + (acc[2].x + acc[3].x)) +
              ((acc[4].x + acc[5].x) + (acc[6].x + acc[7].x));
        a.y = ((acc[0].y + acc[1].y) + (acc[2].y + acc[3].y)) +
              ((acc[4].y + acc[5].y) + (acc[6].y + acc[7].y));
        a.z = ((acc[0].z + acc[1].z) + (acc[2].z + acc[3].z)) +
              ((acc[4].z + acc[5].z) + (acc[6].z + acc[7].z));
        a.w = ((acc[0].w + acc[1].w) + (acc[2].w + acc[3].w)) +
              ((acc[4].w + acc[5].w) + (acc[6].w + acc[7].w));

        float4* op = reinterpret_cast<float4*>(out) + (size_t)node * (F / 4) + slice * 8 + l8;
        if (PASS == 0) {
            *op = a;  // raw partial
        } else {
            const float4 p = *op;
            const float nm = norm[node];
            float4 o;
            o.x = (p.x + a.x) * nm + bb.x;
            o.y = (p.y + a.y) * nm + bb.y;
            o.z = (p.z + a.z) * nm + bb.z;
            o.w = (p.w + a.w) * nm + bb.w;
            if (RELU) {
                o.x = fmaxf(o.x, 0.f); o.y = fmaxf(o.y, 0.f);
                o.z = fmaxf(o.z, 0.f); o.w = fmaxf(o.w, 0.f);
            }
            *op = o;
        }
    }
}

extern "C" void kernel_launch(void* const* d_in, const int* in_sizes, int n_in,
                              void* d_out, int out_size, void* d_ws, size_t ws_size,
                              hipStream_t stream) {
    const float* features = (const float*)d_in[0];
    const int*   src      = (const int*)d_in[1];
    const int*   dst      = (const int*)d_in[2];
    const float* W1 = (const float*)d_in[3];
    const float* b1 = (const float*)d_in[4];
    const float* W2 = (const float*)d_in[5];
    const float* b2 = (const float*)d_in[6];
    const float* W3 = (const float*)d_in[7];
    const float* b3 = (const float*)d_in[8];
    float* out = (float*)d_out;

    auto align256 = [](size_t x) { return (x + 255) / 256 * 256; };
    char* ws = (char*)d_ws;
    size_t off = 0;
    float* norm    = (float*)(ws + off); off += align256((size_t)N_NODES * 4);
    int*   bcnt    = (int*)(ws + off);   off += align256((size_t)NBUCKET * 4);
    int*   bbase   = (int*)(ws + off);   off += align256((size_t)NBUCKET * 4);
    int*   bcursor = (int*)(ws + off);   off += align256((size_t)NBUCKET * 4);
    int*   rowptr  = (int*)(ws + off);   off += align256(((size_t)N_NODES + 1) * 4);
    int*   rowmid  = (int*)(ws + off);   off += align256((size_t)N_NODES * 4);
    int*   etmp    = (int*)(ws + off);   off += align256((size_t)N_EDGES * 4);
    int*   esrc    = (int*)(ws + off);   off += align256((size_t)N_EDGES * 4);
    float* buf0    = (float*)(ws + off); off += (size_t)N_NODES * 128 * 4;
    float* buf1    = (float*)(ws + off);

    const int row_blks = (N_NODES + 63) / 64;  // 782
    const int chunks = (N_NODES + 95) / 96;    // span 96 -> 3 nodes per 8-lane group

    // ---- CSR build (bucket counting sort, src-half ordered) + norm ----
    hipMemsetAsync(bcnt, 0, (size_t)NBUCKET * 4, stream);
    bucket_count<<<EDGE_BLKS, 256, 0, stream>>>(dst, bcnt, N_EDGES);
    bucket_scan<<<1, 256, 0, stream>>>(bcnt, bbase, bcursor, NBUCKET);
    partition_kernel<<<EDGE_BLKS, 256, 0, stream>>>(src, dst, bcursor, etmp, N_EDGES);
    bucket_build<<<NBUCKET, 256, 0, stream>>>(etmp, bbase, rowptr, rowmid, esrc, norm,
                                              N_NODES, NBUCKET, N_EDGES);

    // ---- Layer 1 ----
    gemm_rownorm<128><<<row_blks * 2, 256, 0, stream>>>(features, W1, norm, buf0, N_NODES);
    aggregate_pass<128, true, 0><<<chunks * 4, 256, 0, stream>>>(buf0, rowptr, rowmid, esrc, norm, b1, buf1, N_NODES, chunks);
    aggregate_pass<128, true, 1><<<chunks * 4, 256, 0, stream>>>(buf0, rowptr, rowmid, esrc, norm, b1, buf1, N_NODES, chunks);

    // ---- Layer 2 ----
    gemm_rownorm<128><<<row_blks * 2, 256, 0, stream>>>(buf1, W2, norm, buf0, N_NODES);
    aggregate_pass<128, true, 0><<<chunks * 4, 256, 0, stream>>>(buf0, rowptr, rowmid, esrc, norm, b2, buf1, N_NODES, chunks);
    aggregate_pass<128, true, 1><<<chunks * 4, 256, 0, stream>>>(buf0, rowptr, rowmid, esrc, norm, b2, buf1, N_NODES, chunks);

    // ---- Layer 3 (64 cols) ----
    gemm_rownorm<64><<<row_blks, 256, 0, stream>>>(buf1, W3, norm, buf0, N_NODES);
    aggregate_pass<64, false, 0><<<chunks * 2, 256, 0, stream>>>(buf0, rowptr, rowmid, esrc, norm, b3, out, N_NODES, chunks);
    aggregate_pass<64, false, 1><<<chunks * 2, 256, 0, stream>>>(buf0, rowptr, rowmid, esrc, norm, b3, out, N_NODES, chunks);
}

// Round 14
// 245.420 us; speedup vs baseline: 1.1402x; 1.1402x over previous
//
#include <hip/hip_runtime.h>

#define N_NODES 50000
#define N_EDGES 800000
#define NBUCKET 196           // ceil(N_NODES / 256); bucket b = dst in [b*256,(b+1)*256)
#define EPB 4096              // edges per block in bucket_count / partition (16/thread)
#define EDGE_BLKS ((N_EDGES + EPB - 1) / EPB)  // 196

__device__ __forceinline__ int wave_incl_scan(int v, int lane) {
#pragma unroll
    for (int off = 1; off < 64; off <<= 1) {
        int t = __shfl_up(v, off, 64);
        if (lane >= off) v += t;
    }
    return v;
}

// ---------- CSR build via bucket counting sort ----------

__global__ __launch_bounds__(256) void bucket_count(const int* __restrict__ dst,
                                                    int* __restrict__ bcnt, int nedges) {
    __shared__ int h[NBUCKET];
    for (int i = threadIdx.x; i < NBUCKET; i += 256) h[i] = 0;
    __syncthreads();
    const int eb = blockIdx.x * EPB;
#pragma unroll
    for (int i = 0; i < 16; ++i) {
        int e = eb + i * 256 + threadIdx.x;
        if (e < nedges) atomicAdd(&h[dst[e] >> 8], 1);
    }
    __syncthreads();
    for (int i = threadIdx.x; i < NBUCKET; i += 256)
        if (h[i]) atomicAdd(&bcnt[i], h[i]);
}

__global__ __launch_bounds__(256) void bucket_scan(const int* __restrict__ bcnt,
                                                   int* __restrict__ bbase,
                                                   int* __restrict__ bcursor, int nb) {
    const int i = threadIdx.x;
    const int lane = i & 63;
    const int w = i >> 6;
    int v = (i < nb) ? bcnt[i] : 0;
    int s = wave_incl_scan(v, lane);
    __shared__ int ws[4];
    if (lane == 63) ws[w] = s;
    __syncthreads();
    int add = 0;
#pragma unroll
    for (int k = 0; k < 4; ++k)
        if (k < w) add += ws[k];
    if (i < nb) {
        int excl = s + add - v;
        bbase[i] = excl;
        bcursor[i] = excl;
    }
}

__global__ __launch_bounds__(256) void partition_kernel(const int* __restrict__ src,
                                                        const int* __restrict__ dst,
                                                        int* __restrict__ bcursor,
                                                        int* __restrict__ etmp, int nedges) {
    __shared__ int h[NBUCKET];
    __shared__ int rbase[NBUCKET];
    for (int i = threadIdx.x; i < NBUCKET; i += 256) h[i] = 0;
    __syncthreads();

    const int eb = blockIdx.x * EPB;
    int d[16], s[16];
    bool ok[16];
#pragma unroll
    for (int i = 0; i < 16; ++i) {
        int e = eb + i * 256 + threadIdx.x;
        ok[i] = e < nedges;
        d[i] = ok[i] ? dst[e] : 0;
        s[i] = ok[i] ? src[e] : 0;
        if (ok[i]) atomicAdd(&h[d[i] >> 8], 1);
    }
    __syncthreads();
    for (int i = threadIdx.x; i < NBUCKET; i += 256) {
        rbase[i] = h[i] ? atomicAdd(&bcursor[i], h[i]) : 0;
        h[i] = 0;  // reuse as local cursor
    }
    __syncthreads();
#pragma unroll
    for (int i = 0; i < 16; ++i) {
        if (ok[i]) {
            int b = d[i] >> 8;
            int pos = rbase[b] + atomicAdd(&h[b], 1);
            etmp[pos] = ((d[i] & 255) << 16) | s[i];
        }
    }
}

__global__ __launch_bounds__(256) void bucket_build(const int* __restrict__ etmp,
                                                    const int* __restrict__ bbase,
                                                    int* __restrict__ rowptr,
                                                    int* __restrict__ esrc,
                                                    float* __restrict__ norm,
                                                    int nnodes, int nbuckets, int nedges) {
    const int b = blockIdx.x;
    const int nodebase = b * 256;
    const int nloc = min(256, nnodes - nodebase);
    const int ebeg = bbase[b];
    const int eend = (b + 1 < nbuckets) ? bbase[b + 1] : nedges;

    __shared__ int h[256];
    __shared__ int cur[256];
    h[threadIdx.x] = 0;
    __syncthreads();

    for (int e = ebeg + threadIdx.x; e < eend; e += 256)
        atomicAdd(&h[etmp[e] >> 16], 1);
    __syncthreads();

    const int lane = threadIdx.x & 63;
    const int w = threadIdx.x >> 6;
    int v = h[threadIdx.x];
    int sc = wave_incl_scan(v, lane);
    __shared__ int ws[4];
    if (lane == 63) ws[w] = sc;
    __syncthreads();
    int add = 0;
#pragma unroll
    for (int k = 0; k < 4; ++k)
        if (k < w) add += ws[k];
    const int excl = sc + add - v;

    if (threadIdx.x < nloc) {
        rowptr[nodebase + threadIdx.x] = ebeg + excl;
        norm[nodebase + threadIdx.x] = v > 0 ? rsqrtf((float)v) : 0.0f;
        if (nodebase + threadIdx.x == nnodes - 1) rowptr[nnodes] = ebeg + excl + v;
    }
    cur[threadIdx.x] = excl;
    __syncthreads();

    for (int e = ebeg + threadIdx.x; e < eend; e += 256) {
        int rec = etmp[e];
        int pos = ebeg + atomicAdd(&cur[rec >> 16], 1);
        esrc[pos] = rec & 0xFFFF;
    }
}

// ---------- GEMM with output row-scale, W staged in LDS, 2-deep X pipeline ----------
// Block = 64 rows x 64 cols (OUT=128 split into 2 col-halves).
// Output: OUT/32 slabs of [nrows x 32] floats (slice-major, 128 B rows).
template <int OUT>
__global__ __launch_bounds__(256) void gemm_rownorm(const float* __restrict__ X,
                                                    const float* __restrict__ W,
                                                    const float* __restrict__ norm,
                                                    float* __restrict__ C, int nrows) {
    constexpr int NHALF = OUT / 64;          // 2 for OUT=128, 1 for OUT=64
    const int half = (NHALF > 1) ? (blockIdx.x % NHALF) : 0;
    const int rowblk = blockIdx.x / NHALF;

    __shared__ float Wlds[128 * 64];  // 32 KB

    const int t = threadIdx.x;

    {
        const float4* __restrict__ Wg = reinterpret_cast<const float4*>(W);
        float4* Wl = reinterpret_cast<float4*>(Wlds);
#pragma unroll
        for (int s = 0; s < 8; ++s) {
            int idx = s * 256 + t;          // 0..2047
            int k  = idx >> 4;              // W row
            int cg = idx & 15;              // float4 within 64 cols
            Wl[idx] = Wg[k * (OUT / 4) + half * 16 + cg];
        }
    }
    __syncthreads();

    const int tc = t & 15;
    const int tr = t >> 4;
    const int rowbase = rowblk * 64 + tr * 4;
    const int lastrow = nrows - 1;

    float4 acc[4];
#pragma unroll
    for (int i = 0; i < 4; ++i) acc[i] = make_float4(0.f, 0.f, 0.f, 0.f);

    const float4* __restrict__ X4 = reinterpret_cast<const float4*>(X);
    const float4* __restrict__ Wl4 = reinterpret_cast<const float4*>(Wlds);
    int rIdx[4];
#pragma unroll
    for (int i = 0; i < 4; ++i) {
        int r = rowbase + i;
        rIdx[i] = r < lastrow ? r : lastrow;
    }

    // 2-deep software pipeline: xa holds tile kk, xb holds tile kk+1.
    float4 xa[4], xb[4];
#pragma unroll
    for (int i = 0; i < 4; ++i) xa[i] = X4[(size_t)rIdx[i] * 32 + 0];

    for (int kk = 0; kk < 32; kk += 2) {
        // prefetch kk+1 while computing kk
#pragma unroll
        for (int i = 0; i < 4; ++i) xb[i] = X4[(size_t)rIdx[i] * 32 + (kk + 1)];
#pragma unroll
        for (int j = 0; j < 4; ++j) {
            const float4 w0 = Wl4[(kk * 4 + j) * 16 + tc];
#pragma unroll
            for (int i = 0; i < 4; ++i) {
                const float* xp = reinterpret_cast<const float*>(&xa[i]);
                const float xs = xp[j];
                acc[i].x += xs * w0.x;
                acc[i].y += xs * w0.y;
                acc[i].z += xs * w0.z;
                acc[i].w += xs * w0.w;
            }
        }
        // prefetch kk+2 while computing kk+1 (clamped; extra load harmless)
        const int kn = (kk + 2 < 32) ? (kk + 2) : 31;
#pragma unroll
        for (int i = 0; i < 4; ++i) xa[i] = X4[(size_t)rIdx[i] * 32 + kn];
#pragma unroll
        for (int j = 0; j < 4; ++j) {
            const float4 w0 = Wl4[((kk + 1) * 4 + j) * 16 + tc];
#pragma unroll
            for (int i = 0; i < 4; ++i) {
                const float* xp = reinterpret_cast<const float*>(&xb[i]);
                const float xs = xp[j];
                acc[i].x += xs * w0.x;
                acc[i].y += xs * w0.y;
                acc[i].z += xs * w0.z;
                acc[i].w += xs * w0.w;
            }
        }
    }

    float4* __restrict__ C4 = reinterpret_cast<float4*>(C);
    const size_t slab = (size_t)nrows * 8;
    const int s0  = half * 2 + (tc >> 3);
    const int w0i = tc & 7;
#pragma unroll
    for (int i = 0; i < 4; ++i) {
        int r = rowbase + i;
        if (r < nrows) {
            const float nm = norm[r];
            float4 o = acc[i];
            o.x *= nm; o.y *= nm; o.z *= nm; o.w *= nm;
            C4[(size_t)s0 * slab + (size_t)r * 8 + w0i] = o;
        }
    }
}

// ---------- Column-sliced gather-aggregate, 128 B granules ----------
template <int F, bool RELU>
__global__ __launch_bounds__(256) void aggregate_sliced(const float* __restrict__ feat,
                                                        const int* __restrict__ rowptr,
                                                        const int* __restrict__ esrc,
                                                        const float* __restrict__ norm,
                                                        const float* __restrict__ b,
                                                        float* __restrict__ out,
                                                        int nnodes, int nchunks) {
    constexpr int NSLICE = F / 32;
    const int slice = blockIdx.x % NSLICE;
    const int chunk = blockIdx.x / NSLICE;
    const int span  = (nnodes + nchunks - 1) / nchunks;
    const int nbeg  = chunk * span;
    const int nend  = min(nnodes, nbeg + span);

    const int grp = threadIdx.x >> 3;
    const int l8  = threadIdx.x & 7;

    const float4* __restrict__ slab4 =
        reinterpret_cast<const float4*>(feat) + (size_t)slice * nnodes * 8;
    const float4 bb = reinterpret_cast<const float4*>(b)[slice * 8 + l8];

    for (int node = nbeg + grp; node < nend; node += 32) {
        const int beg = rowptr[node];
        const int end = rowptr[node + 1];

        float4 acc[8];
#pragma unroll
        for (int i = 0; i < 8; ++i) acc[i] = make_float4(0.f, 0.f, 0.f, 0.f);

        for (int e = beg; e < end; e += 8) {
            int idx[8];
#pragma unroll
            for (int i = 0; i < 8; ++i) {
                int ee = e + i;
                idx[i] = esrc[ee < end ? ee : end - 1];
            }
            float4 v[8];
#pragma unroll
            for (int i = 0; i < 8; ++i) v[i] = slab4[(size_t)idx[i] * 8 + l8];
#pragma unroll
            for (int i = 0; i < 8; ++i) {
                if (e + i < end) {
                    acc[i].x += v[i].x; acc[i].y += v[i].y;
                    acc[i].z += v[i].z; acc[i].w += v[i].w;
                }
            }
        }

        float4 a;
        a.x = ((acc[0].x + acc[1].x) + (acc[2].x + acc[3].x)) +
              ((acc[4].x + acc[5].x) + (acc[6].x + acc[7].x));
        a.y = ((acc[0].y + acc[1].y) + (acc[2].y + acc[3].y)) +
              ((acc[4].y + acc[5].y) + (acc[6].y + acc[7].y));
        a.z = ((acc[0].z + acc[1].z) + (acc[2].z + acc[3].z)) +
              ((acc[4].z + acc[5].z) + (acc[6].z + acc[7].z));
        a.w = ((acc[0].w + acc[1].w) + (acc[2].w + acc[3].w)) +
              ((acc[4].w + acc[5].w) + (acc[6].w + acc[7].w));

        const float nm = norm[node];
        float4 o;
        o.x = a.x * nm + bb.x;
        o.y = a.y * nm + bb.y;
        o.z = a.z * nm + bb.z;
        o.w = a.w * nm + bb.w;
        if (RELU) {
            o.x = fmaxf(o.x, 0.f); o.y = fmaxf(o.y, 0.f);
            o.z = fmaxf(o.z, 0.f); o.w = fmaxf(o.w, 0.f);
        }
        reinterpret_cast<float4*>(out)[(size_t)node * (F / 4) + slice * 8 + l8] = o;
    }
}

extern "C" void kernel_launch(void* const* d_in, const int* in_sizes, int n_in,
                              void* d_out, int out_size, void* d_ws, size_t ws_size,
                              hipStream_t stream) {
    const float* features = (const float*)d_in[0];
    const int*   src      = (const int*)d_in[1];
    const int*   dst      = (const int*)d_in[2];
    const float* W1 = (const float*)d_in[3];
    const float* b1 = (const float*)d_in[4];
    const float* W2 = (const float*)d_in[5];
    const float* b2 = (const float*)d_in[6];
    const float* W3 = (const float*)d_in[7];
    const float* b3 = (const float*)d_in[8];
    float* out = (float*)d_out;

    auto align256 = [](size_t x) { return (x + 255) / 256 * 256; };
    char* ws = (char*)d_ws;
    size_t off = 0;
    float* norm    = (float*)(ws + off); off += align256((size_t)N_NODES * 4);
    int*   bcnt    = (int*)(ws + off);   off += align256((size_t)NBUCKET * 4);
    int*   bbase   = (int*)(ws + off);   off += align256((size_t)NBUCKET * 4);
    int*   bcursor = (int*)(ws + off);   off += align256((size_t)NBUCKET * 4);
    int*   rowptr  = (int*)(ws + off);   off += align256(((size_t)N_NODES + 1) * 4);
    int*   etmp    = (int*)(ws + off);   off += align256((size_t)N_EDGES * 4);
    int*   esrc    = (int*)(ws + off);   off += align256((size_t)N_EDGES * 4);
    float* buf0    = (float*)(ws + off); off += (size_t)N_NODES * 128 * 4;
    float* buf1    = (float*)(ws + off);

    const int row_blks = (N_NODES + 63) / 64;  // 782
    const int chunks = (N_NODES + 95) / 96;    // span 96 -> 3 nodes per 8-lane group

    // ---- CSR build (bucket counting sort) + norm ----
    hipMemsetAsync(bcnt, 0, (size_t)NBUCKET * 4, stream);
    bucket_count<<<EDGE_BLKS, 256, 0, stream>>>(dst, bcnt, N_EDGES);
    bucket_scan<<<1, 256, 0, stream>>>(bcnt, bbase, bcursor, NBUCKET);
    partition_kernel<<<EDGE_BLKS, 256, 0, stream>>>(src, dst, bcursor, etmp, N_EDGES);
    bucket_build<<<NBUCKET, 256, 0, stream>>>(etmp, bbase, rowptr, esrc, norm,
                                              N_NODES, NBUCKET, N_EDGES);

    // ---- Layer 1 ----
    gemm_rownorm<128><<<row_blks * 2, 256, 0, stream>>>(features, W1, norm, buf0, N_NODES);
    aggregate_sliced<128, true><<<chunks * 4, 256, 0, stream>>>(buf0, rowptr, esrc, norm, b1, buf1, N_NODES, chunks);

    // ---- Layer 2 ----
    gemm_rownorm<128><<<row_blks * 2, 256, 0, stream>>>(buf1, W2, norm, buf0, N_NODES);
    aggregate_sliced<128, true><<<chunks * 4, 256, 0, stream>>>(buf0, rowptr, esrc, norm, b2, buf1, N_NODES, chunks);

    // ---- Layer 3 (64 cols) ----
    gemm_rownorm<64><<<row_blks, 256, 0, stream>>>(buf1, W3, norm, buf0, N_NODES);
    aggregate_sliced<64, false><<<chunks * 2, 256, 0, stream>>>(buf0, rowptr, esrc, norm, b3, out, N_NODES, chunks);
}

// Round 15
// 220.671 us; speedup vs baseline: 1.2681x; 1.1122x over previous
//
#include <hip/hip_runtime.h>

#define N_NODES 50000
#define N_EDGES 800000
#define NBUCKET 196           // ceil(N_NODES / 256); bucket b = dst in [b*256,(b+1)*256)
#define EPB 4096              // edges per block in bucket_count / partition (16/thread)
#define EDGE_BLKS ((N_EDGES + EPB - 1) / EPB)  // 196

__device__ __forceinline__ int wave_incl_scan(int v, int lane) {
#pragma unroll
    for (int off = 1; off < 64; off <<= 1) {
        int t = __shfl_up(v, off, 64);
        if (lane >= off) v += t;
    }
    return v;
}

// fp32 -> bf16 (round-to-nearest-even), as raw ushort
__device__ __forceinline__ unsigned short f2bf(float f) {
    unsigned int u = __float_as_uint(f);
    u += 0x7FFFu + ((u >> 16) & 1u);
    return (unsigned short)(u >> 16);
}

// ---------- CSR build via bucket counting sort ----------

__global__ __launch_bounds__(256) void bucket_count(const int* __restrict__ dst,
                                                    int* __restrict__ bcnt, int nedges) {
    __shared__ int h[NBUCKET];
    for (int i = threadIdx.x; i < NBUCKET; i += 256) h[i] = 0;
    __syncthreads();
    const int eb = blockIdx.x * EPB;
#pragma unroll
    for (int i = 0; i < 16; ++i) {
        int e = eb + i * 256 + threadIdx.x;
        if (e < nedges) atomicAdd(&h[dst[e] >> 8], 1);
    }
    __syncthreads();
    for (int i = threadIdx.x; i < NBUCKET; i += 256)
        if (h[i]) atomicAdd(&bcnt[i], h[i]);
}

__global__ __launch_bounds__(256) void bucket_scan(const int* __restrict__ bcnt,
                                                   int* __restrict__ bbase,
                                                   int* __restrict__ bcursor, int nb) {
    const int i = threadIdx.x;
    const int lane = i & 63;
    const int w = i >> 6;
    int v = (i < nb) ? bcnt[i] : 0;
    int s = wave_incl_scan(v, lane);
    __shared__ int ws[4];
    if (lane == 63) ws[w] = s;
    __syncthreads();
    int add = 0;
#pragma unroll
    for (int k = 0; k < 4; ++k)
        if (k < w) add += ws[k];
    if (i < nb) {
        int excl = s + add - v;
        bbase[i] = excl;
        bcursor[i] = excl;
    }
}

__global__ __launch_bounds__(256) void partition_kernel(const int* __restrict__ src,
                                                        const int* __restrict__ dst,
                                                        int* __restrict__ bcursor,
                                                        int* __restrict__ etmp, int nedges) {
    __shared__ int h[NBUCKET];
    __shared__ int rbase[NBUCKET];
    for (int i = threadIdx.x; i < NBUCKET; i += 256) h[i] = 0;
    __syncthreads();

    const int eb = blockIdx.x * EPB;
    int d[16], s[16];
    bool ok[16];
#pragma unroll
    for (int i = 0; i < 16; ++i) {
        int e = eb + i * 256 + threadIdx.x;
        ok[i] = e < nedges;
        d[i] = ok[i] ? dst[e] : 0;
        s[i] = ok[i] ? src[e] : 0;
        if (ok[i]) atomicAdd(&h[d[i] >> 8], 1);
    }
    __syncthreads();
    for (int i = threadIdx.x; i < NBUCKET; i += 256) {
        rbase[i] = h[i] ? atomicAdd(&bcursor[i], h[i]) : 0;
        h[i] = 0;  // reuse as local cursor
    }
    __syncthreads();
#pragma unroll
    for (int i = 0; i < 16; ++i) {
        if (ok[i]) {
            int b = d[i] >> 8;
            int pos = rbase[b] + atomicAdd(&h[b], 1);
            etmp[pos] = ((d[i] & 255) << 16) | s[i];
        }
    }
}

__global__ __launch_bounds__(256) void bucket_build(const int* __restrict__ etmp,
                                                    const int* __restrict__ bbase,
                                                    int* __restrict__ rowptr,
                                                    int* __restrict__ esrc,
                                                    float* __restrict__ norm,
                                                    int nnodes, int nbuckets, int nedges) {
    const int b = blockIdx.x;
    const int nodebase = b * 256;
    const int nloc = min(256, nnodes - nodebase);
    const int ebeg = bbase[b];
    const int eend = (b + 1 < nbuckets) ? bbase[b + 1] : nedges;

    __shared__ int h[256];
    __shared__ int cur[256];
    h[threadIdx.x] = 0;
    __syncthreads();

    for (int e = ebeg + threadIdx.x; e < eend; e += 256)
        atomicAdd(&h[etmp[e] >> 16], 1);
    __syncthreads();

    const int lane = threadIdx.x & 63;
    const int w = threadIdx.x >> 6;
    int v = h[threadIdx.x];
    int sc = wave_incl_scan(v, lane);
    __shared__ int ws[4];
    if (lane == 63) ws[w] = sc;
    __syncthreads();
    int add = 0;
#pragma unroll
    for (int k = 0; k < 4; ++k)
        if (k < w) add += ws[k];
    const int excl = sc + add - v;

    if (threadIdx.x < nloc) {
        rowptr[nodebase + threadIdx.x] = ebeg + excl;
        norm[nodebase + threadIdx.x] = v > 0 ? rsqrtf((float)v) : 0.0f;
        if (nodebase + threadIdx.x == nnodes - 1) rowptr[nnodes] = ebeg + excl + v;
    }
    cur[threadIdx.x] = excl;
    __syncthreads();

    for (int e = ebeg + threadIdx.x; e < eend; e += 256) {
        int rec = etmp[e];
        int pos = ebeg + atomicAdd(&cur[rec >> 16], 1);
        esrc[pos] = rec & 0xFFFF;
    }
}

// ---------- GEMM with output row-scale, W staged in LDS, bf16 slice-major out ----------
// Block = 64 rows x 64 cols (OUT=128 split into 2 col-halves).
// Output: OUT/32 slabs of [nrows x 32] bf16 (slice-major, 64 B rows -> 3.2 MB slab, L2-fit).
template <int OUT>
__global__ __launch_bounds__(256) void gemm_rownorm(const float* __restrict__ X,
                                                    const float* __restrict__ W,
                                                    const float* __restrict__ norm,
                                                    unsigned short* __restrict__ C, int nrows) {
    constexpr int NHALF = OUT / 64;          // 2 for OUT=128, 1 for OUT=64
    const int half = (NHALF > 1) ? (blockIdx.x % NHALF) : 0;
    const int rowblk = blockIdx.x / NHALF;

    __shared__ float Wlds[128 * 64];  // 32 KB

    const int t = threadIdx.x;

    {
        const float4* __restrict__ Wg = reinterpret_cast<const float4*>(W);
        float4* Wl = reinterpret_cast<float4*>(Wlds);
#pragma unroll
        for (int s = 0; s < 8; ++s) {
            int idx = s * 256 + t;          // 0..2047
            int k  = idx >> 4;              // W row
            int cg = idx & 15;              // float4 within 64 cols
            Wl[idx] = Wg[k * (OUT / 4) + half * 16 + cg];
        }
    }
    __syncthreads();

    const int tc = t & 15;
    const int tr = t >> 4;
    const int rowbase = rowblk * 64 + tr * 4;
    const int lastrow = nrows - 1;

    float4 acc[4];
#pragma unroll
    for (int i = 0; i < 4; ++i) acc[i] = make_float4(0.f, 0.f, 0.f, 0.f);

    const float4* __restrict__ X4 = reinterpret_cast<const float4*>(X);
    const float4* __restrict__ Wl4 = reinterpret_cast<const float4*>(Wlds);
    int rIdx[4];
#pragma unroll
    for (int i = 0; i < 4; ++i) {
        int r = rowbase + i;
        rIdx[i] = r < lastrow ? r : lastrow;
    }

    // 2-deep software pipeline: xa holds tile kk, xb holds tile kk+1.
    float4 xa[4], xb[4];
#pragma unroll
    for (int i = 0; i < 4; ++i) xa[i] = X4[(size_t)rIdx[i] * 32 + 0];

    for (int kk = 0; kk < 32; kk += 2) {
#pragma unroll
        for (int i = 0; i < 4; ++i) xb[i] = X4[(size_t)rIdx[i] * 32 + (kk + 1)];
#pragma unroll
        for (int j = 0; j < 4; ++j) {
            const float4 w0 = Wl4[(kk * 4 + j) * 16 + tc];
#pragma unroll
            for (int i = 0; i < 4; ++i) {
                const float* xp = reinterpret_cast<const float*>(&xa[i]);
                const float xs = xp[j];
                acc[i].x += xs * w0.x;
                acc[i].y += xs * w0.y;
                acc[i].z += xs * w0.z;
                acc[i].w += xs * w0.w;
            }
        }
        const int kn = (kk + 2 < 32) ? (kk + 2) : 31;
#pragma unroll
        for (int i = 0; i < 4; ++i) xa[i] = X4[(size_t)rIdx[i] * 32 + kn];
#pragma unroll
        for (int j = 0; j < 4; ++j) {
            const float4 w0 = Wl4[((kk + 1) * 4 + j) * 16 + tc];
#pragma unroll
            for (int i = 0; i < 4; ++i) {
                const float* xp = reinterpret_cast<const float*>(&xb[i]);
                const float xs = xp[j];
                acc[i].x += xs * w0.x;
                acc[i].y += xs * w0.y;
                acc[i].z += xs * w0.z;
                acc[i].w += xs * w0.w;
            }
        }
    }

    // bf16 slice-major store: slab s is [nrows x 32] bf16 = nrows*8 ushort4.
    ushort4* __restrict__ C4 = reinterpret_cast<ushort4*>(C);
    const size_t slab = (size_t)nrows * 8;
    const int s0  = half * 2 + (tc >> 3);
    const int w0i = tc & 7;
#pragma unroll
    for (int i = 0; i < 4; ++i) {
        int r = rowbase + i;
        if (r < nrows) {
            const float nm = norm[r];
            float4 o = acc[i];
            ushort4 p;
            p.x = f2bf(o.x * nm);
            p.y = f2bf(o.y * nm);
            p.z = f2bf(o.z * nm);
            p.w = f2bf(o.w * nm);
            C4[(size_t)s0 * slab + (size_t)r * 8 + w0i] = p;
        }
    }
}

// ---------- Column-sliced bf16 gather-aggregate ----------
// feat slice-major bf16 (F/32 slabs of [nnodes x 32] bf16, 64 B rows, 3.2 MB slab).
// slice = blockIdx.x % NSLICE rides block->XCD round-robin: slab L2-resident.
// A 4-lane group owns one node: lane = uint4 (16 B = 8 bf16 cols). 8-deep unroll,
// clamped loads + masked fp32 accumulate. span 128 -> 2 nodes per group.
template <int F, bool RELU>
__global__ __launch_bounds__(256) void aggregate_bf16(const unsigned short* __restrict__ feat,
                                                      const int* __restrict__ rowptr,
                                                      const int* __restrict__ esrc,
                                                      const float* __restrict__ norm,
                                                      const float* __restrict__ b,
                                                      float* __restrict__ out,
                                                      int nnodes, int nchunks) {
    constexpr int NSLICE = F / 32;
    const int slice = blockIdx.x % NSLICE;
    const int chunk = blockIdx.x / NSLICE;
    const int span  = (nnodes + nchunks - 1) / nchunks;
    const int nbeg  = chunk * span;
    const int nend  = min(nnodes, nbeg + span);

    const int grp = threadIdx.x >> 2;   // 64 groups per block
    const int l4  = threadIdx.x & 3;    // uint4 (8 bf16 cols) within 32-col slice

    const uint4* __restrict__ slab4 =
        reinterpret_cast<const uint4*>(feat) + (size_t)slice * nnodes * 4;
    const float4* __restrict__ b4 = reinterpret_cast<const float4*>(b);
    const float4 bb0 = b4[slice * 8 + l4 * 2];
    const float4 bb1 = b4[slice * 8 + l4 * 2 + 1];

    for (int node = nbeg + grp; node < nend; node += 64) {
        const int beg = rowptr[node];
        const int end = rowptr[node + 1];

        float4 aA[8], aB[8];
#pragma unroll
        for (int i = 0; i < 8; ++i) {
            aA[i] = make_float4(0.f, 0.f, 0.f, 0.f);
            aB[i] = make_float4(0.f, 0.f, 0.f, 0.f);
        }

        for (int e = beg; e < end; e += 8) {
            int idx[8];
#pragma unroll
            for (int i = 0; i < 8; ++i) {
                int ee = e + i;
                idx[i] = esrc[ee < end ? ee : end - 1];
            }
            uint4 v[8];
#pragma unroll
            for (int i = 0; i < 8; ++i) v[i] = slab4[(size_t)idx[i] * 4 + l4];
#pragma unroll
            for (int i = 0; i < 8; ++i) {
                if (e + i < end) {
                    aA[i].x += __uint_as_float(v[i].x << 16);
                    aA[i].y += __uint_as_float(v[i].x & 0xFFFF0000u);
                    aA[i].z += __uint_as_float(v[i].y << 16);
                    aA[i].w += __uint_as_float(v[i].y & 0xFFFF0000u);
                    aB[i].x += __uint_as_float(v[i].z << 16);
                    aB[i].y += __uint_as_float(v[i].z & 0xFFFF0000u);
                    aB[i].z += __uint_as_float(v[i].w << 16);
                    aB[i].w += __uint_as_float(v[i].w & 0xFFFF0000u);
                }
            }
        }

        float4 a0, a1;
        a0.x = ((aA[0].x + aA[1].x) + (aA[2].x + aA[3].x)) + ((aA[4].x + aA[5].x) + (aA[6].x + aA[7].x));
        a0.y = ((aA[0].y + aA[1].y) + (aA[2].y + aA[3].y)) + ((aA[4].y + aA[5].y) + (aA[6].y + aA[7].y));
        a0.z = ((aA[0].z + aA[1].z) + (aA[2].z + aA[3].z)) + ((aA[4].z + aA[5].z) + (aA[6].z + aA[7].z));
        a0.w = ((aA[0].w + aA[1].w) + (aA[2].w + aA[3].w)) + ((aA[4].w + aA[5].w) + (aA[6].w + aA[7].w));
        a1.x = ((aB[0].x + aB[1].x) + (aB[2].x + aB[3].x)) + ((aB[4].x + aB[5].x) + (aB[6].x + aB[7].x));
        a1.y = ((aB[0].y + aB[1].y) + (aB[2].y + aB[3].y)) + ((aB[4].y + aB[5].y) + (aB[6].y + aB[7].y));
        a1.z = ((aB[0].z + aB[1].z) + (aB[2].z + aB[3].z)) + ((aB[4].z + aB[5].z) + (aB[6].z + aB[7].z));
        a1.w = ((aB[0].w + aB[1].w) + (aB[2].w + aB[3].w)) + ((aB[4].w + aB[5].w) + (aB[6].w + aB[7].w));

        const float nm = norm[node];
        float4 o0, o1;
        o0.x = a0.x * nm + bb0.x; o0.y = a0.y * nm + bb0.y;
        o0.z = a0.z * nm + bb0.z; o0.w = a0.w * nm + bb0.w;
        o1.x = a1.x * nm + bb1.x; o1.y = a1.y * nm + bb1.y;
        o1.z = a1.z * nm + bb1.z; o1.w = a1.w * nm + bb1.w;
        if (RELU) {
            o0.x = fmaxf(o0.x, 0.f); o0.y = fmaxf(o0.y, 0.f);
            o0.z = fmaxf(o0.z, 0.f); o0.w = fmaxf(o0.w, 0.f);
            o1.x = fmaxf(o1.x, 0.f); o1.y = fmaxf(o1.y, 0.f);
            o1.z = fmaxf(o1.z, 0.f); o1.w = fmaxf(o1.w, 0.f);
        }
        float4* op = reinterpret_cast<float4*>(out) + (size_t)node * (F / 4) + slice * 8 + l4 * 2;
        op[0] = o0;
        op[1] = o1;
    }
}

extern "C" void kernel_launch(void* const* d_in, const int* in_sizes, int n_in,
                              void* d_out, int out_size, void* d_ws, size_t ws_size,
                              hipStream_t stream) {
    const float* features = (const float*)d_in[0];
    const int*   src      = (const int*)d_in[1];
    const int*   dst      = (const int*)d_in[2];
    const float* W1 = (const float*)d_in[3];
    const float* b1 = (const float*)d_in[4];
    const float* W2 = (const float*)d_in[5];
    const float* b2 = (const float*)d_in[6];
    const float* W3 = (const float*)d_in[7];
    const float* b3 = (const float*)d_in[8];
    float* out = (float*)d_out;

    auto align256 = [](size_t x) { return (x + 255) / 256 * 256; };
    char* ws = (char*)d_ws;
    size_t off = 0;
    float* norm    = (float*)(ws + off); off += align256((size_t)N_NODES * 4);
    int*   bcnt    = (int*)(ws + off);   off += align256((size_t)NBUCKET * 4);
    int*   bbase   = (int*)(ws + off);   off += align256((size_t)NBUCKET * 4);
    int*   bcursor = (int*)(ws + off);   off += align256((size_t)NBUCKET * 4);
    int*   rowptr  = (int*)(ws + off);   off += align256(((size_t)N_NODES + 1) * 4);
    int*   etmp    = (int*)(ws + off);   off += align256((size_t)N_EDGES * 4);
    int*   esrc    = (int*)(ws + off);   off += align256((size_t)N_EDGES * 4);
    unsigned short* slab = (unsigned short*)(ws + off); off += align256((size_t)N_NODES * 128 * 2);
    float* bufF    = (float*)(ws + off); off += (size_t)N_NODES * 128 * 4;

    const int row_blks = (N_NODES + 63) / 64;   // 782
    const int chunks = (N_NODES + 127) / 128;   // span 128 -> 2 nodes per 4-lane group

    // ---- CSR build (bucket counting sort) + norm ----
    hipMemsetAsync(bcnt, 0, (size_t)NBUCKET * 4, stream);
    bucket_count<<<EDGE_BLKS, 256, 0, stream>>>(dst, bcnt, N_EDGES);
    bucket_scan<<<1, 256, 0, stream>>>(bcnt, bbase, bcursor, NBUCKET);
    partition_kernel<<<EDGE_BLKS, 256, 0, stream>>>(src, dst, bcursor, etmp, N_EDGES);
    bucket_build<<<NBUCKET, 256, 0, stream>>>(etmp, bbase, rowptr, esrc, norm,
                                              N_NODES, NBUCKET, N_EDGES);

    // ---- Layer 1: features -> slab (bf16) -> bufF (h1, fp32) ----
    gemm_rownorm<128><<<row_blks * 2, 256, 0, stream>>>(features, W1, norm, slab, N_NODES);
    aggregate_bf16<128, true><<<chunks * 4, 256, 0, stream>>>(slab, rowptr, esrc, norm, b1, bufF, N_NODES, chunks);

    // ---- Layer 2: bufF -> slab (bf16) -> bufF (h2, fp32) ----
    gemm_rownorm<128><<<row_blks * 2, 256, 0, stream>>>(bufF, W2, norm, slab, N_NODES);
    aggregate_bf16<128, true><<<chunks * 4, 256, 0, stream>>>(slab, rowptr, esrc, norm, b2, bufF, N_NODES, chunks);

    // ---- Layer 3: bufF -> slab (bf16, 64 cols) -> d_out (fp32) ----
    gemm_rownorm<64><<<row_blks, 256, 0, stream>>>(bufF, W3, norm, slab, N_NODES);
    aggregate_bf16<64, false><<<chunks * 2, 256, 0, stream>>>(slab, rowptr, esrc, norm, b3, out, N_NODES, chunks);
}

// Round 16
// 203.165 us; speedup vs baseline: 1.3774x; 1.0862x over previous
//
#include <hip/hip_runtime.h>

#define N_NODES 50000
#define N_EDGES 800000
#define NBUCKET 196           // ceil(N_NODES / 256); bucket b = dst in [b*256,(b+1)*256)
#define EPB 4096              // edges per block in bucket_count / partition (16/thread)
#define EDGE_BLKS ((N_EDGES + EPB - 1) / EPB)  // 196

typedef __attribute__((ext_vector_type(8))) short bf16x8;
typedef __attribute__((ext_vector_type(4))) float f32x4;

__device__ __forceinline__ int wave_incl_scan(int v, int lane) {
#pragma unroll
    for (int off = 1; off < 64; off <<= 1) {
        int t = __shfl_up(v, off, 64);
        if (lane >= off) v += t;
    }
    return v;
}

// fp32 -> bf16 (round-to-nearest-even), as raw ushort
__device__ __forceinline__ unsigned short f2bf(float f) {
    unsigned int u = __float_as_uint(f);
    u += 0x7FFFu + ((u >> 16) & 1u);
    return (unsigned short)(u >> 16);
}

// ---------- CSR build via bucket counting sort ----------

__global__ __launch_bounds__(256) void bucket_count(const int* __restrict__ dst,
                                                    int* __restrict__ bcnt, int nedges) {
    __shared__ int h[NBUCKET];
    for (int i = threadIdx.x; i < NBUCKET; i += 256) h[i] = 0;
    __syncthreads();
    const int eb = blockIdx.x * EPB;
#pragma unroll
    for (int i = 0; i < 16; ++i) {
        int e = eb + i * 256 + threadIdx.x;
        if (e < nedges) atomicAdd(&h[dst[e] >> 8], 1);
    }
    __syncthreads();
    for (int i = threadIdx.x; i < NBUCKET; i += 256)
        if (h[i]) atomicAdd(&bcnt[i], h[i]);
}

__global__ __launch_bounds__(256) void bucket_scan(const int* __restrict__ bcnt,
                                                   int* __restrict__ bbase,
                                                   int* __restrict__ bcursor, int nb) {
    const int i = threadIdx.x;
    const int lane = i & 63;
    const int w = i >> 6;
    int v = (i < nb) ? bcnt[i] : 0;
    int s = wave_incl_scan(v, lane);
    __shared__ int ws[4];
    if (lane == 63) ws[w] = s;
    __syncthreads();
    int add = 0;
#pragma unroll
    for (int k = 0; k < 4; ++k)
        if (k < w) add += ws[k];
    if (i < nb) {
        int excl = s + add - v;
        bbase[i] = excl;
        bcursor[i] = excl;
    }
}

__global__ __launch_bounds__(256) void partition_kernel(const int* __restrict__ src,
                                                        const int* __restrict__ dst,
                                                        int* __restrict__ bcursor,
                                                        int* __restrict__ etmp, int nedges) {
    __shared__ int h[NBUCKET];
    __shared__ int rbase[NBUCKET];
    for (int i = threadIdx.x; i < NBUCKET; i += 256) h[i] = 0;
    __syncthreads();

    const int eb = blockIdx.x * EPB;
    int d[16], s[16];
    bool ok[16];
#pragma unroll
    for (int i = 0; i < 16; ++i) {
        int e = eb + i * 256 + threadIdx.x;
        ok[i] = e < nedges;
        d[i] = ok[i] ? dst[e] : 0;
        s[i] = ok[i] ? src[e] : 0;
        if (ok[i]) atomicAdd(&h[d[i] >> 8], 1);
    }
    __syncthreads();
    for (int i = threadIdx.x; i < NBUCKET; i += 256) {
        rbase[i] = h[i] ? atomicAdd(&bcursor[i], h[i]) : 0;
        h[i] = 0;  // reuse as local cursor
    }
    __syncthreads();
#pragma unroll
    for (int i = 0; i < 16; ++i) {
        if (ok[i]) {
            int b = d[i] >> 8;
            int pos = rbase[b] + atomicAdd(&h[b], 1);
            etmp[pos] = ((d[i] & 255) << 16) | s[i];
        }
    }
}

__global__ __launch_bounds__(256) void bucket_build(const int* __restrict__ etmp,
                                                    const int* __restrict__ bbase,
                                                    int* __restrict__ rowptr,
                                                    int* __restrict__ esrc,
                                                    float* __restrict__ norm,
                                                    int nnodes, int nbuckets, int nedges) {
    const int b = blockIdx.x;
    const int nodebase = b * 256;
    const int nloc = min(256, nnodes - nodebase);
    const int ebeg = bbase[b];
    const int eend = (b + 1 < nbuckets) ? bbase[b + 1] : nedges;

    __shared__ int h[256];
    __shared__ int cur[256];
    h[threadIdx.x] = 0;
    __syncthreads();

    for (int e = ebeg + threadIdx.x; e < eend; e += 256)
        atomicAdd(&h[etmp[e] >> 16], 1);
    __syncthreads();

    const int lane = threadIdx.x & 63;
    const int w = threadIdx.x >> 6;
    int v = h[threadIdx.x];
    int sc = wave_incl_scan(v, lane);
    __shared__ int ws[4];
    if (lane == 63) ws[w] = sc;
    __syncthreads();
    int add = 0;
#pragma unroll
    for (int k = 0; k < 4; ++k)
        if (k < w) add += ws[k];
    const int excl = sc + add - v;

    if (threadIdx.x < nloc) {
        rowptr[nodebase + threadIdx.x] = ebeg + excl;
        norm[nodebase + threadIdx.x] = v > 0 ? rsqrtf((float)v) : 0.0f;
        if (nodebase + threadIdx.x == nnodes - 1) rowptr[nnodes] = ebeg + excl + v;
    }
    cur[threadIdx.x] = excl;
    __syncthreads();

    for (int e = ebeg + threadIdx.x; e < eend; e += 256) {
        int rec = etmp[e];
        int pos = ebeg + atomicAdd(&cur[rec >> 16], 1);
        esrc[pos] = rec & 0xFFFF;
    }
}

// ---------- W prep: transpose fp32 [128][OUT] -> bf16 Wt [OUT][128] ----------
__global__ __launch_bounds__(256) void wprep(const float* __restrict__ W,
                                             unsigned short* __restrict__ Wt, int OUT) {
    int i = blockIdx.x * 256 + threadIdx.x;  // over OUT*128
    if (i < OUT * 128) {
        int n = i >> 7;
        int k = i & 127;
        Wt[i] = f2bf(W[k * OUT + n]);
    }
}

// ---------- MFMA GEMM: C_slab = bf16( norm[r] * X @ W ) ----------
// Block = 256 thr (4 waves) x 64 rows x full OUT. X staged fp32 in LDS (XOR
// swizzle (row&7)<<5); Wt staged bf16 (XOR (col&7)<<4). X exactness via hi/lo
// bf16 split (2 chained MFMAs); W single bf16. mfma_f32_16x16x32_bf16:
// A: row=l&15, k=(l>>4)*8+j ; B: col=l&15, same k ; D: col=l&15, row=(l>>4)*4+r.
// Output: OUT/32 slabs of [nrows x 32] bf16 (slice-major, matches aggregate).
template <int OUT>
__global__ __launch_bounds__(256) void gemm_mfma(const float* __restrict__ X,
                                                 const unsigned short* __restrict__ Wt,
                                                 const float* __restrict__ norm,
                                                 unsigned short* __restrict__ C, int nrows) {
    constexpr int NT = OUT / 16;
    __shared__ float Xlds[64 * 128];             // 32 KB
    __shared__ unsigned short Wlds[OUT * 128];   // 32/16 KB

    const int t = threadIdx.x;
    const int rowbase = blockIdx.x * 64;
    const int lastrow = nrows - 1;

    // ---- stage X (fp32, swizzled) ----
    {
        const float4* __restrict__ X4 = reinterpret_cast<const float4*>(X);
        char* xb = reinterpret_cast<char*>(Xlds);
        for (int i = t; i < 2048; i += 256) {
            int row = i >> 5;
            int grow = rowbase + row;
            grow = grow < lastrow ? grow : lastrow;
            float4 v = X4[(size_t)grow * 32 + (i & 31)];
            int byte = i << 4;
            *reinterpret_cast<float4*>(xb + (byte ^ ((row & 7) << 5))) = v;
        }
    }
    // ---- stage Wt (bf16, swizzled) ----
    {
        const ushort4* __restrict__ Wt4 = reinterpret_cast<const ushort4*>(Wt);
        char* wb = reinterpret_cast<char*>(Wlds);
        for (int i = t; i < OUT * 32; i += 256) {
            ushort4 v = Wt4[i];
            int byte = i << 3;
            int n = byte >> 8;
            *reinterpret_cast<ushort4*>(wb + (byte ^ ((n & 7) << 4))) = v;
        }
    }
    __syncthreads();

    const int w   = t >> 6;
    const int l   = t & 63;
    const int r16 = l & 15;
    const int ks  = l >> 4;

    const int lrow = w * 16 + r16;
    const char* xb  = reinterpret_cast<const char*>(Xlds);
    const char* wbp = reinterpret_cast<const char*>(Wlds);

    // A fragments: hi/lo bf16 split of X (X exact)
    bf16x8 ahi[4], alo[4];
#pragma unroll
    for (int kk = 0; kk < 4; ++kk) {
        int byteA = lrow * 512 + kk * 128 + ks * 32;
        byteA ^= ((lrow & 7) << 5);
        float4 v0 = *reinterpret_cast<const float4*>(xb + byteA);
        float4 v1 = *reinterpret_cast<const float4*>(xb + byteA + 16);
        float xv[8] = {v0.x, v0.y, v0.z, v0.w, v1.x, v1.y, v1.z, v1.w};
#pragma unroll
        for (int j = 0; j < 8; ++j) {
            unsigned short h = f2bf(xv[j]);
            float hf = __uint_as_float(((unsigned int)h) << 16);
            unsigned short lo = f2bf(xv[j] - hf);
            ahi[kk][j] = (short)h;
            alo[kk][j] = (short)lo;
        }
    }

    // this lane's 4 output rows
    const int orow0 = rowbase + w * 16 + ks * 4;
    float nrm[4];
#pragma unroll
    for (int r = 0; r < 4; ++r) {
        int rr = orow0 + r;
        nrm[r] = (rr < nrows) ? norm[rr] : 0.0f;
    }

    const size_t slab = (size_t)nrows * 32;  // ushorts per slab
#pragma unroll
    for (int n = 0; n < NT; ++n) {
        f32x4 acc = {0.f, 0.f, 0.f, 0.f};
        const int col = n * 16 + r16;
#pragma unroll
        for (int kk = 0; kk < 4; ++kk) {
            int byteB = col * 256 + kk * 64 + ks * 16;
            byteB ^= ((col & 7) << 4);
            bf16x8 bfrag = *reinterpret_cast<const bf16x8*>(wbp + byteB);
            acc = __builtin_amdgcn_mfma_f32_16x16x32_bf16(alo[kk], bfrag, acc, 0, 0, 0);
            acc = __builtin_amdgcn_mfma_f32_16x16x32_bf16(ahi[kk], bfrag, acc, 0, 0, 0);
        }
        const int s  = col >> 5;
        const int cs = col & 31;
        unsigned short* cp = C + (size_t)s * slab + (size_t)orow0 * 32 + cs;
#pragma unroll
        for (int r = 0; r < 4; ++r) {
            if (orow0 + r < nrows)
                cp[(size_t)r * 32] = f2bf(acc[r] * nrm[r]);
        }
    }
}

// ---------- Column-sliced bf16 gather-aggregate (unchanged from r15) ----------
template <int F, bool RELU>
__global__ __launch_bounds__(256) void aggregate_bf16(const unsigned short* __restrict__ feat,
                                                      const int* __restrict__ rowptr,
                                                      const int* __restrict__ esrc,
                                                      const float* __restrict__ norm,
                                                      const float* __restrict__ b,
                                                      float* __restrict__ out,
                                                      int nnodes, int nchunks) {
    constexpr int NSLICE = F / 32;
    const int slice = blockIdx.x % NSLICE;
    const int chunk = blockIdx.x / NSLICE;
    const int span  = (nnodes + nchunks - 1) / nchunks;
    const int nbeg  = chunk * span;
    const int nend  = min(nnodes, nbeg + span);

    const int grp = threadIdx.x >> 2;   // 64 groups per block
    const int l4  = threadIdx.x & 3;    // uint4 (8 bf16 cols) within 32-col slice

    const uint4* __restrict__ slab4 =
        reinterpret_cast<const uint4*>(feat) + (size_t)slice * nnodes * 4;
    const float4* __restrict__ b4 = reinterpret_cast<const float4*>(b);
    const float4 bb0 = b4[slice * 8 + l4 * 2];
    const float4 bb1 = b4[slice * 8 + l4 * 2 + 1];

    for (int node = nbeg + grp; node < nend; node += 64) {
        const int beg = rowptr[node];
        const int end = rowptr[node + 1];

        float4 aA[8], aB[8];
#pragma unroll
        for (int i = 0; i < 8; ++i) {
            aA[i] = make_float4(0.f, 0.f, 0.f, 0.f);
            aB[i] = make_float4(0.f, 0.f, 0.f, 0.f);
        }

        for (int e = beg; e < end; e += 8) {
            int idx[8];
#pragma unroll
            for (int i = 0; i < 8; ++i) {
                int ee = e + i;
                idx[i] = esrc[ee < end ? ee : end - 1];
            }
            uint4 v[8];
#pragma unroll
            for (int i = 0; i < 8; ++i) v[i] = slab4[(size_t)idx[i] * 4 + l4];
#pragma unroll
            for (int i = 0; i < 8; ++i) {
                if (e + i < end) {
                    aA[i].x += __uint_as_float(v[i].x << 16);
                    aA[i].y += __uint_as_float(v[i].x & 0xFFFF0000u);
                    aA[i].z += __uint_as_float(v[i].y << 16);
                    aA[i].w += __uint_as_float(v[i].y & 0xFFFF0000u);
                    aB[i].x += __uint_as_float(v[i].z << 16);
                    aB[i].y += __uint_as_float(v[i].z & 0xFFFF0000u);
                    aB[i].z += __uint_as_float(v[i].w << 16);
                    aB[i].w += __uint_as_float(v[i].w & 0xFFFF0000u);
                }
            }
        }

        float4 a0, a1;
        a0.x = ((aA[0].x + aA[1].x) + (aA[2].x + aA[3].x)) + ((aA[4].x + aA[5].x) + (aA[6].x + aA[7].x));
        a0.y = ((aA[0].y + aA[1].y) + (aA[2].y + aA[3].y)) + ((aA[4].y + aA[5].y) + (aA[6].y + aA[7].y));
        a0.z = ((aA[0].z + aA[1].z) + (aA[2].z + aA[3].z)) + ((aA[4].z + aA[5].z) + (aA[6].z + aA[7].z));
        a0.w = ((aA[0].w + aA[1].w) + (aA[2].w + aA[3].w)) + ((aA[4].w + aA[5].w) + (aA[6].w + aA[7].w));
        a1.x = ((aB[0].x + aB[1].x) + (aB[2].x + aB[3].x)) + ((aB[4].x + aB[5].x) + (aB[6].x + aB[7].x));
        a1.y = ((aB[0].y + aB[1].y) + (aB[2].y + aB[3].y)) + ((aB[4].y + aB[5].y) + (aB[6].y + aB[7].y));
        a1.z = ((aB[0].z + aB[1].z) + (aB[2].z + aB[3].z)) + ((aB[4].z + aB[5].z) + (aB[6].z + aB[7].z));
        a1.w = ((aB[0].w + aB[1].w) + (aB[2].w + aB[3].w)) + ((aB[4].w + aB[5].w) + (aB[6].w + aB[7].w));

        const float nm = norm[node];
        float4 o0, o1;
        o0.x = a0.x * nm + bb0.x; o0.y = a0.y * nm + bb0.y;
        o0.z = a0.z * nm + bb0.z; o0.w = a0.w * nm + bb0.w;
        o1.x = a1.x * nm + bb1.x; o1.y = a1.y * nm + bb1.y;
        o1.z = a1.z * nm + bb1.z; o1.w = a1.w * nm + bb1.w;
        if (RELU) {
            o0.x = fmaxf(o0.x, 0.f); o0.y = fmaxf(o0.y, 0.f);
            o0.z = fmaxf(o0.z, 0.f); o0.w = fmaxf(o0.w, 0.f);
            o1.x = fmaxf(o1.x, 0.f); o1.y = fmaxf(o1.y, 0.f);
            o1.z = fmaxf(o1.z, 0.f); o1.w = fmaxf(o1.w, 0.f);
        }
        float4* op = reinterpret_cast<float4*>(out) + (size_t)node * (F / 4) + slice * 8 + l4 * 2;
        op[0] = o0;
        op[1] = o1;
    }
}

extern "C" void kernel_launch(void* const* d_in, const int* in_sizes, int n_in,
                              void* d_out, int out_size, void* d_ws, size_t ws_size,
                              hipStream_t stream) {
    const float* features = (const float*)d_in[0];
    const int*   src      = (const int*)d_in[1];
    const int*   dst      = (const int*)d_in[2];
    const float* W1 = (const float*)d_in[3];
    const float* b1 = (const float*)d_in[4];
    const float* W2 = (const float*)d_in[5];
    const float* b2 = (const float*)d_in[6];
    const float* W3 = (const float*)d_in[7];
    const float* b3 = (const float*)d_in[8];
    float* out = (float*)d_out;

    auto align256 = [](size_t x) { return (x + 255) / 256 * 256; };
    char* ws = (char*)d_ws;
    size_t off = 0;
    float* norm    = (float*)(ws + off); off += align256((size_t)N_NODES * 4);
    int*   bcnt    = (int*)(ws + off);   off += align256((size_t)NBUCKET * 4);
    int*   bbase   = (int*)(ws + off);   off += align256((size_t)NBUCKET * 4);
    int*   bcursor = (int*)(ws + off);   off += align256((size_t)NBUCKET * 4);
    int*   rowptr  = (int*)(ws + off);   off += align256(((size_t)N_NODES + 1) * 4);
    int*   etmp    = (int*)(ws + off);   off += align256((size_t)N_EDGES * 4);
    int*   esrc    = (int*)(ws + off);   off += align256((size_t)N_EDGES * 4);
    unsigned short* wt1 = (unsigned short*)(ws + off); off += align256((size_t)128 * 128 * 2);
    unsigned short* wt2 = (unsigned short*)(ws + off); off += align256((size_t)128 * 128 * 2);
    unsigned short* wt3 = (unsigned short*)(ws + off); off += align256((size_t)64 * 128 * 2);
    unsigned short* slab = (unsigned short*)(ws + off); off += align256((size_t)N_NODES * 128 * 2);
    float* bufF    = (float*)(ws + off); off += (size_t)N_NODES * 128 * 4;

    const int row_blks = (N_NODES + 63) / 64;   // 782
    const int chunks = (N_NODES + 127) / 128;   // span 128 -> 2 nodes per 4-lane group

    // ---- W prep (bf16 transposed weights) ----
    wprep<<<64, 256, 0, stream>>>(W1, wt1, 128);
    wprep<<<64, 256, 0, stream>>>(W2, wt2, 128);
    wprep<<<32, 256, 0, stream>>>(W3, wt3, 64);

    // ---- CSR build (bucket counting sort) + norm ----
    hipMemsetAsync(bcnt, 0, (size_t)NBUCKET * 4, stream);
    bucket_count<<<EDGE_BLKS, 256, 0, stream>>>(dst, bcnt, N_EDGES);
    bucket_scan<<<1, 256, 0, stream>>>(bcnt, bbase, bcursor, NBUCKET);
    partition_kernel<<<EDGE_BLKS, 256, 0, stream>>>(src, dst, bcursor, etmp, N_EDGES);
    bucket_build<<<NBUCKET, 256, 0, stream>>>(etmp, bbase, rowptr, esrc, norm,
                                              N_NODES, NBUCKET, N_EDGES);

    // ---- Layer 1: features -> slab (bf16) -> bufF (h1, fp32) ----
    gemm_mfma<128><<<row_blks, 256, 0, stream>>>(features, wt1, norm, slab, N_NODES);
    aggregate_bf16<128, true><<<chunks * 4, 256, 0, stream>>>(slab, rowptr, esrc, norm, b1, bufF, N_NODES, chunks);

    // ---- Layer 2: bufF -> slab (bf16) -> bufF (h2, fp32) ----
    gemm_mfma<128><<<row_blks, 256, 0, stream>>>(bufF, wt2, norm, slab, N_NODES);
    aggregate_bf16<128, true><<<chunks * 4, 256, 0, stream>>>(slab, rowptr, esrc, norm, b2, bufF, N_NODES, chunks);

    // ---- Layer 3: bufF -> slab (bf16, 64 cols) -> d_out (fp32) ----
    gemm_mfma<64><<<row_blks, 256, 0, stream>>>(bufF, wt3, norm, slab, N_NODES);
    aggregate_bf16<64, false><<<chunks * 2, 256, 0, stream>>>(slab, rowptr, esrc, norm, b3, out, N_NODES, chunks);
}

// Round 17
// 182.544 us; speedup vs baseline: 1.5330x; 1.1130x over previous
//
#include <hip/hip_runtime.h>

#define N_NODES 50000
#define N_EDGES 800000
#define NBUCKET 196           // ceil(N_NODES / 256); bucket b = dst in [b*256,(b+1)*256)
#define EPB 4096              // edges per block in bucket_count / partition (16/thread)
#define EDGE_BLKS ((N_EDGES + EPB - 1) / EPB)  // 196

typedef __attribute__((ext_vector_type(8))) short bf16x8;
typedef __attribute__((ext_vector_type(4))) float f32x4;

__device__ __forceinline__ int wave_incl_scan(int v, int lane) {
#pragma unroll
    for (int off = 1; off < 64; off <<= 1) {
        int t = __shfl_up(v, off, 64);
        if (lane >= off) v += t;
    }
    return v;
}

// fp32 -> bf16 (round-to-nearest-even), as raw ushort
__device__ __forceinline__ unsigned short f2bf(float f) {
    unsigned int u = __float_as_uint(f);
    u += 0x7FFFu + ((u >> 16) & 1u);
    return (unsigned short)(u >> 16);
}

// ---------- CSR build via bucket counting sort ----------

__global__ __launch_bounds__(256) void bucket_count(const int* __restrict__ dst,
                                                    int* __restrict__ bcnt, int nedges) {
    __shared__ int h[NBUCKET];
    for (int i = threadIdx.x; i < NBUCKET; i += 256) h[i] = 0;
    __syncthreads();
    const int eb = blockIdx.x * EPB;
#pragma unroll
    for (int i = 0; i < 16; ++i) {
        int e = eb + i * 256 + threadIdx.x;
        if (e < nedges) atomicAdd(&h[dst[e] >> 8], 1);
    }
    __syncthreads();
    for (int i = threadIdx.x; i < NBUCKET; i += 256)
        if (h[i]) atomicAdd(&bcnt[i], h[i]);
}

__global__ __launch_bounds__(256) void bucket_scan(const int* __restrict__ bcnt,
                                                   int* __restrict__ bbase,
                                                   int* __restrict__ bcursor, int nb) {
    const int i = threadIdx.x;
    const int lane = i & 63;
    const int w = i >> 6;
    int v = (i < nb) ? bcnt[i] : 0;
    int s = wave_incl_scan(v, lane);
    __shared__ int ws[4];
    if (lane == 63) ws[w] = s;
    __syncthreads();
    int add = 0;
#pragma unroll
    for (int k = 0; k < 4; ++k)
        if (k < w) add += ws[k];
    if (i < nb) {
        int excl = s + add - v;
        bbase[i] = excl;
        bcursor[i] = excl;
    }
}

__global__ __launch_bounds__(256) void partition_kernel(const int* __restrict__ src,
                                                        const int* __restrict__ dst,
                                                        int* __restrict__ bcursor,
                                                        int* __restrict__ etmp, int nedges) {
    __shared__ int h[NBUCKET];
    __shared__ int rbase[NBUCKET];
    for (int i = threadIdx.x; i < NBUCKET; i += 256) h[i] = 0;
    __syncthreads();

    const int eb = blockIdx.x * EPB;
    int d[16], s[16];
    bool ok[16];
#pragma unroll
    for (int i = 0; i < 16; ++i) {
        int e = eb + i * 256 + threadIdx.x;
        ok[i] = e < nedges;
        d[i] = ok[i] ? dst[e] : 0;
        s[i] = ok[i] ? src[e] : 0;
        if (ok[i]) atomicAdd(&h[d[i] >> 8], 1);
    }
    __syncthreads();
    for (int i = threadIdx.x; i < NBUCKET; i += 256) {
        rbase[i] = h[i] ? atomicAdd(&bcursor[i], h[i]) : 0;
        h[i] = 0;  // reuse as local cursor
    }
    __syncthreads();
#pragma unroll
    for (int i = 0; i < 16; ++i) {
        if (ok[i]) {
            int b = d[i] >> 8;
            int pos = rbase[b] + atomicAdd(&h[b], 1);
            etmp[pos] = ((d[i] & 255) << 16) | s[i];
        }
    }
}

__global__ __launch_bounds__(256) void bucket_build(const int* __restrict__ etmp,
                                                    const int* __restrict__ bbase,
                                                    int* __restrict__ rowptr,
                                                    unsigned short* __restrict__ esrc,
                                                    float* __restrict__ norm,
                                                    int nnodes, int nbuckets, int nedges) {
    const int b = blockIdx.x;
    const int nodebase = b * 256;
    const int nloc = min(256, nnodes - nodebase);
    const int ebeg = bbase[b];
    const int eend = (b + 1 < nbuckets) ? bbase[b + 1] : nedges;

    __shared__ int h[256];
    __shared__ int cur[256];
    h[threadIdx.x] = 0;
    __syncthreads();

    for (int e = ebeg + threadIdx.x; e < eend; e += 256)
        atomicAdd(&h[etmp[e] >> 16], 1);
    __syncthreads();

    const int lane = threadIdx.x & 63;
    const int w = threadIdx.x >> 6;
    int v = h[threadIdx.x];
    int sc = wave_incl_scan(v, lane);
    __shared__ int ws[4];
    if (lane == 63) ws[w] = sc;
    __syncthreads();
    int add = 0;
#pragma unroll
    for (int k = 0; k < 4; ++k)
        if (k < w) add += ws[k];
    const int excl = sc + add - v;

    if (threadIdx.x < nloc) {
        rowptr[nodebase + threadIdx.x] = ebeg + excl;
        norm[nodebase + threadIdx.x] = v > 0 ? rsqrtf((float)v) : 0.0f;
        if (nodebase + threadIdx.x == nnodes - 1) rowptr[nnodes] = ebeg + excl + v;
    }
    cur[threadIdx.x] = excl;
    __syncthreads();

    for (int e = ebeg + threadIdx.x; e < eend; e += 256) {
        int rec = etmp[e];
        int pos = ebeg + atomicAdd(&cur[rec >> 16], 1);
        esrc[pos] = (unsigned short)(rec & 0xFFFF);
    }
}

// ---------- W prep (all three): transpose fp32 [128][OUT] -> bf16 Wt [OUT][128] ----------
__global__ __launch_bounds__(256) void wprep_all(const float* __restrict__ W1,
                                                 const float* __restrict__ W2,
                                                 const float* __restrict__ W3,
                                                 unsigned short* __restrict__ wt1,
                                                 unsigned short* __restrict__ wt2,
                                                 unsigned short* __restrict__ wt3) {
    int i = blockIdx.x * 256 + threadIdx.x;
    if (i < 16384) {
        wt1[i] = f2bf(W1[(i & 127) * 128 + (i >> 7)]);
    } else if (i < 32768) {
        int j = i - 16384;
        wt2[j] = f2bf(W2[(j & 127) * 128 + (j >> 7)]);
    } else if (i < 40960) {
        int j = i - 32768;
        wt3[j] = f2bf(W3[(j & 127) * 64 + (j >> 7)]);
    }
}

// ---------- MFMA GEMM: C_slab = bf16( norm[r] * X @ W ) ----------
// LDS holds only Wt (bf16, XOR swizzle (col&7)<<4). A-fragments load DIRECTLY
// from global X (wave = 16 rows x 128 B contiguous per kk). X exactness via
// hi/lo bf16 split (2 chained MFMAs). mfma_f32_16x16x32_bf16 layouts:
// A: row=l&15, k=(l>>4)*8+j ; B: col=l&15, same k ; D: col=l&15, row=(l>>4)*4+r.
// OUT=128: block = 32 rows, 4 waves = 2 row-groups x 2 col-halves.
// OUT=64 : block = 64 rows, 4 waves = 4 row-groups x 1 col-half.
// Output: OUT/32 slabs of [nrows x 32] bf16 (slice-major, matches aggregate).
template <int OUT>
__global__ __launch_bounds__(256) void gemm_mfma(const float* __restrict__ X,
                                                 const unsigned short* __restrict__ Wt,
                                                 const float* __restrict__ norm,
                                                 unsigned short* __restrict__ C, int nrows) {
    constexpr int ROWS = (OUT == 128) ? 32 : 64;
    __shared__ unsigned short Wlds[OUT * 128];   // 32/16 KB

    const int t = threadIdx.x;
    const int rowbase = blockIdx.x * ROWS;
    const int lastrow = nrows - 1;

    // ---- stage Wt (bf16, swizzled) ----
    {
        const ushort4* __restrict__ Wt4 = reinterpret_cast<const ushort4*>(Wt);
        char* wb = reinterpret_cast<char*>(Wlds);
        for (int i = t; i < OUT * 32; i += 256) {
            ushort4 v = Wt4[i];
            int byte = i << 3;
            int n = byte >> 8;
            *reinterpret_cast<ushort4*>(wb + (byte ^ ((n & 7) << 4))) = v;
        }
    }
    __syncthreads();

    const int w   = t >> 6;
    const int l   = t & 63;
    const int r16 = l & 15;
    const int ks  = l >> 4;

    const int rw = (OUT == 128) ? (w & 1) : w;   // row-group within block
    const int ch = (OUT == 128) ? (w >> 1) : 0;  // col-half (64 cols each)

    int grow = rowbase + rw * 16 + r16;
    grow = grow < lastrow ? grow : lastrow;

    const float4* __restrict__ X4 = reinterpret_cast<const float4*>(X);
    const char* wbp = reinterpret_cast<const char*>(Wlds);

    // A fragments direct from global: hi/lo bf16 split (X exact)
    bf16x8 ahi[4], alo[4];
#pragma unroll
    for (int kk = 0; kk < 4; ++kk) {
        float4 v0 = X4[(size_t)grow * 32 + kk * 8 + ks * 2];
        float4 v1 = X4[(size_t)grow * 32 + kk * 8 + ks * 2 + 1];
        float xv[8] = {v0.x, v0.y, v0.z, v0.w, v1.x, v1.y, v1.z, v1.w};
#pragma unroll
        for (int j = 0; j < 8; ++j) {
            unsigned short h = f2bf(xv[j]);
            float hf = __uint_as_float(((unsigned int)h) << 16);
            unsigned short lo = f2bf(xv[j] - hf);
            ahi[kk][j] = (short)h;
            alo[kk][j] = (short)lo;
        }
    }

    // this lane's 4 output rows
    const int orow0 = rowbase + rw * 16 + ks * 4;
    float nrm[4];
#pragma unroll
    for (int r = 0; r < 4; ++r) {
        int rr = orow0 + r;
        nrm[r] = (rr < nrows) ? norm[rr] : 0.0f;
    }

    const size_t slab = (size_t)nrows * 32;  // ushorts per slab
#pragma unroll
    for (int n = 0; n < 4; ++n) {
        f32x4 acc = {0.f, 0.f, 0.f, 0.f};
        const int col = (ch * 4 + n) * 16 + r16;
#pragma unroll
        for (int kk = 0; kk < 4; ++kk) {
            int byteB = col * 256 + kk * 64 + ks * 16;
            byteB ^= ((col & 7) << 4);
            bf16x8 bfrag = *reinterpret_cast<const bf16x8*>(wbp + byteB);
            acc = __builtin_amdgcn_mfma_f32_16x16x32_bf16(alo[kk], bfrag, acc, 0, 0, 0);
            acc = __builtin_amdgcn_mfma_f32_16x16x32_bf16(ahi[kk], bfrag, acc, 0, 0, 0);
        }
        const int s  = col >> 5;
        const int cs = col & 31;
        unsigned short* cp = C + (size_t)s * slab + (size_t)orow0 * 32 + cs;
#pragma unroll
        for (int r = 0; r < 4; ++r) {
            if (orow0 + r < nrows)
                cp[(size_t)r * 32] = f2bf(acc[r] * nrm[r]);
        }
    }
}

// ---------- Column-sliced bf16 gather-aggregate ----------
// feat slice-major bf16 (F/32 slabs of [nnodes x 32] bf16, 64 B rows, 3.2 MB slab).
// slice = blockIdx.x % NSLICE rides block->XCD round-robin: slab L2-resident.
// A 4-lane group owns one node: lane = uint4 (16 B = 8 bf16 cols). 8-deep unroll,
// clamped loads + masked fp32 accumulate. span 128 -> 2 nodes per group.
template <int F, bool RELU>
__global__ __launch_bounds__(256) void aggregate_bf16(const unsigned short* __restrict__ feat,
                                                      const int* __restrict__ rowptr,
                                                      const unsigned short* __restrict__ esrc,
                                                      const float* __restrict__ norm,
                                                      const float* __restrict__ b,
                                                      float* __restrict__ out,
                                                      int nnodes, int nchunks) {
    constexpr int NSLICE = F / 32;
    const int slice = blockIdx.x % NSLICE;
    const int chunk = blockIdx.x / NSLICE;
    const int span  = (nnodes + nchunks - 1) / nchunks;
    const int nbeg  = chunk * span;
    const int nend  = min(nnodes, nbeg + span);

    const int grp = threadIdx.x >> 2;   // 64 groups per block
    const int l4  = threadIdx.x & 3;    // uint4 (8 bf16 cols) within 32-col slice

    const uint4* __restrict__ slab4 =
        reinterpret_cast<const uint4*>(feat) + (size_t)slice * nnodes * 4;
    const float4* __restrict__ b4 = reinterpret_cast<const float4*>(b);
    const float4 bb0 = b4[slice * 8 + l4 * 2];
    const float4 bb1 = b4[slice * 8 + l4 * 2 + 1];

    for (int node = nbeg + grp; node < nend; node += 64) {
        const int beg = rowptr[node];
        const int end = rowptr[node + 1];

        float4 aA[8], aB[8];
#pragma unroll
        for (int i = 0; i < 8; ++i) {
            aA[i] = make_float4(0.f, 0.f, 0.f, 0.f);
            aB[i] = make_float4(0.f, 0.f, 0.f, 0.f);
        }

        for (int e = beg; e < end; e += 8) {
            int idx[8];
#pragma unroll
            for (int i = 0; i < 8; ++i) {
                int ee = e + i;
                idx[i] = esrc[ee < end ? ee : end - 1];
            }
            uint4 v[8];
#pragma unroll
            for (int i = 0; i < 8; ++i) v[i] = slab4[(size_t)idx[i] * 4 + l4];
#pragma unroll
            for (int i = 0; i < 8; ++i) {
                if (e + i < end) {
                    aA[i].x += __uint_as_float(v[i].x << 16);
                    aA[i].y += __uint_as_float(v[i].x & 0xFFFF0000u);
                    aA[i].z += __uint_as_float(v[i].y << 16);
                    aA[i].w += __uint_as_float(v[i].y & 0xFFFF0000u);
                    aB[i].x += __uint_as_float(v[i].z << 16);
                    aB[i].y += __uint_as_float(v[i].z & 0xFFFF0000u);
                    aB[i].z += __uint_as_float(v[i].w << 16);
                    aB[i].w += __uint_as_float(v[i].w & 0xFFFF0000u);
                }
            }
        }

        float4 a0, a1;
        a0.x = ((aA[0].x + aA[1].x) + (aA[2].x + aA[3].x)) + ((aA[4].x + aA[5].x) + (aA[6].x + aA[7].x));
        a0.y = ((aA[0].y + aA[1].y) + (aA[2].y + aA[3].y)) + ((aA[4].y + aA[5].y) + (aA[6].y + aA[7].y));
        a0.z = ((aA[0].z + aA[1].z) + (aA[2].z + aA[3].z)) + ((aA[4].z + aA[5].z) + (aA[6].z + aA[7].z));
        a0.w = ((aA[0].w + aA[1].w) + (aA[2].w + aA[3].w)) + ((aA[4].w + aA[5].w) + (aA[6].w + aA[7].w));
        a1.x = ((aB[0].x + aB[1].x) + (aB[2].x + aB[3].x)) + ((aB[4].x + aB[5].x) + (aB[6].x + aB[7].x));
        a1.y = ((aB[0].y + aB[1].y) + (aB[2].y + aB[3].y)) + ((aB[4].y + aB[5].y) + (aB[6].y + aB[7].y));
        a1.z = ((aB[0].z + aB[1].z) + (aB[2].z + aB[3].z)) + ((aB[4].z + aB[5].z) + (aB[6].z + aB[7].z));
        a1.w = ((aB[0].w + aB[1].w) + (aB[2].w + aB[3].w)) + ((aB[4].w + aB[5].w) + (aB[6].w + aB[7].w));

        const float nm = norm[node];
        float4 o0, o1;
        o0.x = a0.x * nm + bb0.x; o0.y = a0.y * nm + bb0.y;
        o0.z = a0.z * nm + bb0.z; o0.w = a0.w * nm + bb0.w;
        o1.x = a1.x * nm + bb1.x; o1.y = a1.y * nm + bb1.y;
        o1.z = a1.z * nm + bb1.z; o1.w = a1.w * nm + bb1.w;
        if (RELU) {
            o0.x = fmaxf(o0.x, 0.f); o0.y = fmaxf(o0.y, 0.f);
            o0.z = fmaxf(o0.z, 0.f); o0.w = fmaxf(o0.w, 0.f);
            o1.x = fmaxf(o1.x, 0.f); o1.y = fmaxf(o1.y, 0.f);
            o1.z = fmaxf(o1.z, 0.f); o1.w = fmaxf(o1.w, 0.f);
        }
        float4* op = reinterpret_cast<float4*>(out) + (size_t)node * (F / 4) + slice * 8 + l4 * 2;
        op[0] = o0;
        op[1] = o1;
    }
}

extern "C" void kernel_launch(void* const* d_in, const int* in_sizes, int n_in,
                              void* d_out, int out_size, void* d_ws, size_t ws_size,
                              hipStream_t stream) {
    const float* features = (const float*)d_in[0];
    const int*   src      = (const int*)d_in[1];
    const int*   dst      = (const int*)d_in[2];
    const float* W1 = (const float*)d_in[3];
    const float* b1 = (const float*)d_in[4];
    const float* W2 = (const float*)d_in[5];
    const float* b2 = (const float*)d_in[6];
    const float* W3 = (const float*)d_in[7];
    const float* b3 = (const float*)d_in[8];
    float* out = (float*)d_out;

    auto align256 = [](size_t x) { return (x + 255) / 256 * 256; };
    char* ws = (char*)d_ws;
    size_t off = 0;
    float* norm    = (float*)(ws + off); off += align256((size_t)N_NODES * 4);
    int*   bcnt    = (int*)(ws + off);   off += align256((size_t)NBUCKET * 4);
    int*   bbase   = (int*)(ws + off);   off += align256((size_t)NBUCKET * 4);
    int*   bcursor = (int*)(ws + off);   off += align256((size_t)NBUCKET * 4);
    int*   rowptr  = (int*)(ws + off);   off += align256(((size_t)N_NODES + 1) * 4);
    int*   etmp    = (int*)(ws + off);   off += align256((size_t)N_EDGES * 4);
    unsigned short* esrc = (unsigned short*)(ws + off); off += align256((size_t)N_EDGES * 2);
    unsigned short* wt1 = (unsigned short*)(ws + off); off += align256((size_t)128 * 128 * 2);
    unsigned short* wt2 = (unsigned short*)(ws + off); off += align256((size_t)128 * 128 * 2);
    unsigned short* wt3 = (unsigned short*)(ws + off); off += align256((size_t)64 * 128 * 2);
    unsigned short* slab = (unsigned short*)(ws + off); off += align256((size_t)N_NODES * 128 * 2);
    float* bufF    = (float*)(ws + off); off += (size_t)N_NODES * 128 * 4;

    const int gemm128_blks = (N_NODES + 31) / 32;  // 1563
    const int gemm64_blks  = (N_NODES + 63) / 64;  // 782
    const int chunks = (N_NODES + 127) / 128;      // span 128 -> 2 nodes per 4-lane group

    // ---- W prep (bf16 transposed weights, one kernel) ----
    wprep_all<<<160, 256, 0, stream>>>(W1, W2, W3, wt1, wt2, wt3);

    // ---- CSR build (bucket counting sort) + norm ----
    hipMemsetAsync(bcnt, 0, (size_t)NBUCKET * 4, stream);
    bucket_count<<<EDGE_BLKS, 256, 0, stream>>>(dst, bcnt, N_EDGES);
    bucket_scan<<<1, 256, 0, stream>>>(bcnt, bbase, bcursor, NBUCKET);
    partition_kernel<<<EDGE_BLKS, 256, 0, stream>>>(src, dst, bcursor, etmp, N_EDGES);
    bucket_build<<<NBUCKET, 256, 0, stream>>>(etmp, bbase, rowptr, esrc, norm,
                                              N_NODES, NBUCKET, N_EDGES);

    // ---- Layer 1: features -> slab (bf16) -> bufF (h1, fp32) ----
    gemm_mfma<128><<<gemm128_blks, 256, 0, stream>>>(features, wt1, norm, slab, N_NODES);
    aggregate_bf16<128, true><<<chunks * 4, 256, 0, stream>>>(slab, rowptr, esrc, norm, b1, bufF, N_NODES, chunks);

    // ---- Layer 2: bufF -> slab (bf16) -> bufF (h2, fp32) ----
    gemm_mfma<128><<<gemm128_blks, 256, 0, stream>>>(bufF, wt2, norm, slab, N_NODES);
    aggregate_bf16<128, true><<<chunks * 4, 256, 0, stream>>>(slab, rowptr, esrc, norm, b2, bufF, N_NODES, chunks);

    // ---- Layer 3: bufF -> slab (bf16, 64 cols) -> d_out (fp32) ----
    gemm_mfma<64><<<gemm64_blks, 256, 0, stream>>>(bufF, wt3, norm, slab, N_NODES);
    aggregate_bf16<64, false><<<chunks * 2, 256, 0, stream>>>(slab, rowptr, esrc, norm, b3, out, N_NODES, chunks);
}